// Round 2
// baseline (106.742 us; speedup 1.0000x reference)
//
#include <hip/hip_runtime.h>
#include <math.h>

#define NV 512
#define KC 32
#define NB 192
#define LOG2PI 1.8378770664093453f

// ws float layout — all per-block EXCLUSIVE slices, fully overwritten every
// launch (no zero-init needed; harness 0xAA poison is harmless):
//   WS_G: 96 GEMM slices, stride 1088: [smtile 32x32 =1024][v 32][mm 1]
//   WS_S: 24 stats slices, stride 608:  [u 512][sx1 32][sx2 32][xx 1]
//   WS_P: prep slice:                   [coef 32][logdet 1]
#define WS_G 0
#define G_STRIDE 1088
#define WS_S 104448
#define S_STRIDE 608
#define WS_P 119040

__global__ __launch_bounds__(256) void partial_kernel(
    const float* __restrict__ X, const float* __restrict__ C,
    const float* __restrict__ G, const float* __restrict__ W,
    const float* __restrict__ bias, const float* __restrict__ sigma,
    const float* __restrict__ rho, float* __restrict__ wsF)
{
    const int bid = blockIdx.x, tid = threadIdx.x;
    __shared__ int asg[NV];
    __shared__ float Gs[KC * KC];
    __shared__ float XsT[32][34];   // [k][row], stride 34: 8B-aligned float2, 2-way bank alias only
    __shared__ float WsT[32][34];   // [k][col]
    __shared__ float smtile[32 * KC];
    __shared__ float varr[32];
    __shared__ float redw[8];
    __shared__ float smrows[8][KC];

    // cluster assignment from one-hot C (exact: values are 0.0/1.0)
    for (int n = tid; n < NV; n += 256) {
        const float* row = C + n * KC;
        float a = 0.f;
        #pragma unroll
        for (int c = 0; c < KC; ++c) a += row[c] * (float)c;
        asg[n] = (int)(a + 0.5f);
    }

    if (bid < 96) {
        // ---- GEMM tile: rows b0..b0+31 of mean, cols i0..i0+31
        for (int l = tid; l < KC * KC; l += 256) Gs[l] = G[l];
        for (int l = tid; l < 32 * KC; l += 256) smtile[l] = 0.f;
        if (tid < 32) varr[tid] = 0.f;
        if (tid < 8) redw[tid] = 0.f;
        __syncthreads();
        const int i0 = (bid & 15) * 32, b0 = (bid >> 4) * 32;
        const int tx = tid & 15, ty = tid >> 4;   // 16x16 threads, 2x2 micro-tile
        float a00 = 0.f, a01 = 0.f, a10 = 0.f, a11 = 0.f;
        for (int kt = 0; kt < 16; ++kt) {
            const int k0 = kt * 32;
            #pragma unroll
            for (int p = 0; p < 4; ++p) {
                const int l = tid + p * 256;
                const int r2 = l >> 5, c2 = l & 31;
                XsT[c2][r2] = X[(b0 + r2) * NV + k0 + c2];
                WsT[c2][r2] = W[(i0 + r2) * NV + k0 + c2]
                            * Gs[asg[i0 + r2] * KC + asg[k0 + c2]];
            }
            __syncthreads();
            #pragma unroll
            for (int kk = 0; kk < 32; ++kk) {
                const float2 xv = *(const float2*)&XsT[kk][ty * 2];
                const float2 wv = *(const float2*)&WsT[kk][tx * 2];
                a00 += xv.x * wv.x; a01 += xv.x * wv.y;
                a10 += xv.y * wv.x; a11 += xv.y * wv.y;
            }
            __syncthreads();
        }
        const int col0 = i0 + tx * 2, col1 = col0 + 1;
        const float bf0 = bias[col0], bf1 = bias[col1];
        const int ci0 = asg[col0], ci1 = asg[col1];
        const int r0 = ty * 2, r1 = r0 + 1;
        const float v00 = a00 + bf0, v01 = a01 + bf1;
        const float v10 = a10 + bf0, v11 = a11 + bf1;
        float mml = v00 * v00 + v01 * v01 + v10 * v10 + v11 * v11;
        atomicAdd(&smtile[r0 * KC + ci0], v00);
        atomicAdd(&smtile[r0 * KC + ci1], v01);
        atomicAdd(&smtile[r1 * KC + ci0], v10);
        atomicAdd(&smtile[r1 * KC + ci1], v11);
        atomicAdd(&varr[tx * 2], v00 + v10);
        atomicAdd(&varr[tx * 2 + 1], v01 + v11);
        for (int off = 32; off; off >>= 1) mml += __shfl_down(mml, off, 64);
        if ((tid & 63) == 0) redw[tid >> 6] = mml;
        __syncthreads();
        float* slice = wsF + WS_G + bid * G_STRIDE;
        for (int l = tid; l < 32 * KC; l += 256) slice[l] = smtile[l];
        if (tid < 32) slice[1024 + tid] = varr[tid];
        if (tid == 0) slice[1056] = redw[0] + redw[1] + redw[2] + redw[3];
    } else if (bid < 120) {
        // ---- X stats: 8 rows -> u-partials, xx, per-row cluster sums -> sx1/sx2
        for (int l = tid; l < 8 * KC; l += 256) ((float*)smrows)[l] = 0.f;
        if (tid < 8) redw[tid] = 0.f;
        __syncthreads();
        const int sb = bid - 96, row0 = sb * 8;
        const int c0 = tid * 2;
        const int ca = asg[c0], cb = asg[c0 + 1];
        float u0 = 0.f, u1 = 0.f, xx = 0.f;
        #pragma unroll
        for (int r = 0; r < 8; ++r) {
            const float2 xv = *(const float2*)(X + (row0 + r) * NV + c0);
            u0 += xv.x; u1 += xv.y;
            xx += xv.x * xv.x + xv.y * xv.y;
            atomicAdd(&smrows[r][ca], xv.x);
            atomicAdd(&smrows[r][cb], xv.y);
        }
        for (int off = 32; off; off >>= 1) xx += __shfl_down(xx, off, 64);
        if ((tid & 63) == 0) redw[tid >> 6] = xx;
        __syncthreads();
        float* slice = wsF + WS_S + sb * S_STRIDE;
        slice[c0] = u0; slice[c0 + 1] = u1;
        if (tid < KC) {
            float s1 = 0.f, s2 = 0.f;
            #pragma unroll
            for (int r = 0; r < 8; ++r) { const float s = smrows[r][tid]; s1 += s; s2 += s * s; }
            slice[512 + tid] = s1;
            slice[544 + tid] = s2;
        }
        if (tid == 0) slice[576] = redw[0] + redw[1] + redw[2] + redw[3];
    } else {
        // ---- prep: cluster counts -> coef, logdet
        __shared__ int cnt[KC];
        __shared__ float ldred[KC];
        if (tid < KC) cnt[tid] = 0;
        __syncthreads();
        for (int n = tid; n < NV; n += 256) atomicAdd(&cnt[asg[n]], 1);
        __syncthreads();
        const float s2v = sigma[0] * sigma[0], rh = rho[0];
        const float av = s2v * (1.f - rh), bv = s2v * rh;
        if (tid < KC) {
            const int nc = cnt[tid];
            wsF[WS_P + tid] = bv / (av * (av + bv * (float)nc));
            ldred[tid] = (float)(nc - 1) * logf(av) + logf(av + bv * (float)nc);
        }
        __syncthreads();
        if (tid == 0) {
            float ld = 0.f;
            for (int c = 0; c < KC; ++c) ld += ldred[c];
            wsF[WS_P + 32] = ld;
        }
    }
}

__global__ __launch_bounds__(512) void finalize_kernel(
    const float* __restrict__ sigma, const float* __restrict__ rho,
    const float* __restrict__ wsF, float* __restrict__ out)
{
    const int tid = threadIdx.x;
    __shared__ float SM1s[KC], SM2s[KC];
    __shared__ float accs[4];   // 0:MM 1:XX 2:cross(u.v) 3:Q
    if (tid < KC) { SM1s[tid] = 0.f; SM2s[tid] = 0.f; }
    if (tid < 4) accs[tid] = 0.f;
    __syncthreads();
    const float* gS = wsF + WS_G;
    const float* sS = wsF + WS_S;
    // assemble sm[b][c] from 16 i-tiles, accumulate SM1/SM2
    #pragma unroll
    for (int w = 0; w < 12; ++w) {
        const int o = tid + w * 512;          // 6144 = 192*32 outputs
        const int b = o >> 5, c = o & 31;
        const float* p = gS + (b >> 5) * 16 * G_STRIDE + (b & 31) * KC + c;
        float s = 0.f;
        #pragma unroll
        for (int it = 0; it < 16; ++it) s += p[it * G_STRIDE];
        atomicAdd(&SM1s[c], s);
        atomicAdd(&SM2s[c], s * s);
    }
    // u, v, cross term
    {
        const int i = tid;                    // 512 threads == NV
        const int it = i >> 5;
        float v = 0.f;
        #pragma unroll
        for (int bt = 0; bt < 6; ++bt) v += gS[(bt * 16 + it) * G_STRIDE + 1024 + (i & 31)];
        float u = 0.f;
        #pragma unroll
        for (int sb = 0; sb < 24; ++sb) u += sS[sb * S_STRIDE + i];
        float cr = u * v;
        for (int off = 32; off; off >>= 1) cr += __shfl_down(cr, off, 64);
        if ((tid & 63) == 0) atomicAdd(&accs[2], cr);
    }
    // MM
    {
        float mm = (tid < 96) ? gS[tid * G_STRIDE + 1056] : 0.f;
        for (int off = 32; off; off >>= 1) mm += __shfl_down(mm, off, 64);
        if ((tid & 63) == 0) atomicAdd(&accs[0], mm);
    }
    // XX
    {
        float xx = (tid < 24) ? sS[tid * S_STRIDE + 576] : 0.f;
        for (int off = 32; off; off >>= 1) xx += __shfl_down(xx, off, 64);
        if ((tid & 63) == 0) atomicAdd(&accs[1], xx);
    }
    __syncthreads();
    // Q term
    float qv = 0.f;
    if (tid < KC) {
        float s1 = 0.f, s2 = 0.f;
        #pragma unroll
        for (int sb = 0; sb < 24; ++sb) {
            s1 += sS[sb * S_STRIDE + 512 + tid];
            s2 += sS[sb * S_STRIDE + 544 + tid];
        }
        const float coef = wsF[WS_P + tid];
        qv = coef * (s2 * (1.f / NB) + SM2s[tid] * (1.f / NB)
                     - 2.f * s1 * SM1s[tid] * (1.f / ((float)NB * (float)NB)));
    }
    for (int off = 16; off; off >>= 1) qv += __shfl_down(qv, off, 64);
    if (tid == 0) atomicAdd(&accs[3], qv);
    __syncthreads();
    if (tid == 0) {
        const float s2v = sigma[0] * sigma[0], rh = rho[0];
        const float av = s2v * (1.f - rh);
        const float meanD2 = accs[1] * (1.f / NB) + accs[0] * (1.f / NB)
                           - 2.f * accs[2] / ((float)NB * (float)NB);
        const float maha = meanD2 / av - accs[3];
        out[0] = -0.5f * (maha + wsF[WS_P + 32] + (float)NV * LOG2PI);
    }
}

extern "C" void kernel_launch(void* const* d_in, const int* in_sizes, int n_in,
                              void* d_out, int out_size, void* d_ws, size_t ws_size,
                              hipStream_t stream) {
    const float* X     = (const float*)d_in[0];
    const float* C     = (const float*)d_in[1];
    const float* G     = (const float*)d_in[2];
    const float* W     = (const float*)d_in[3];
    const float* b     = (const float*)d_in[4];
    const float* sigma = (const float*)d_in[5];
    const float* rho   = (const float*)d_in[6];
    float* wsF = (float*)d_ws;
    float* out = (float*)d_out;

    hipLaunchKernelGGL(partial_kernel, dim3(121), dim3(256), 0, stream,
                       X, C, G, W, b, sigma, rho, wsF);
    hipLaunchKernelGGL(finalize_kernel, dim3(1), dim3(512), 0, stream,
                       sigma, rho, wsF, out);
}

// Round 3
// 86.866 us; speedup vs baseline: 1.2288x; 1.2288x over previous
//
#include <hip/hip_runtime.h>
#include <math.h>

#define NV 512
#define KC 32
#define NB 192
#define LOG2PI 1.8378770664093453f

typedef __attribute__((ext_vector_type(8))) short short8;
typedef __attribute__((ext_vector_type(4))) float float4v;

// ws layout (float units):
#define WS_SM    0        // sm[192*32]: zeroed by prep (node1), atomic-accum by gemm (node2)
#define WS_GV    6144     // 96 slices x 65: [v 64][mm 1]
#define WS_STATS 12400    // 24 slices x 608: [u 512][sx1 32][sx2 32][xx 1]
#define WS_P     27000    // [coef 32][logdet 1]
#define WS_ASG   27040    // int asg[512]
#define WS_XBF   27552    // bf16 X [192*512]  (49152 floats, 16B-aligned)
#define WS_WBF   76704    // bf16 Wm [512*512] (131072 floats, 16B-aligned)

static __device__ inline ushort f2bf(float f) {
    uint u = __float_as_uint(f);
    uint r = (u + 0x7fffu + ((u >> 16) & 1u)) >> 16;   // RNE
    return (ushort)r;
}

// ---------------- node 1: convert + stats + prep ----------------
__global__ __launch_bounds__(256) void prep_kernel(
    const float* __restrict__ X, const float* __restrict__ C,
    const float* __restrict__ G, const float* __restrict__ W,
    const float* __restrict__ bias, const float* __restrict__ sigma,
    const float* __restrict__ rho, float* __restrict__ wsF, int* __restrict__ wsI)
{
    const int bid = blockIdx.x, tid = threadIdx.x;
    __shared__ int asg[NV];
    __shared__ float Gs[KC * KC];
    __shared__ float smrows[8][KC];
    __shared__ float redw[4];

    // cluster assignment from one-hot C (exact 0/1 values)
    for (int n = tid; n < NV; n += 256) {
        const float* row = C + n * KC;
        float a = 0.f;
        #pragma unroll
        for (int c = 0; c < KC; ++c) a += row[c] * (float)c;
        asg[n] = (int)(a + 0.5f);
    }

    if (bid < 24) {
        // ---- convert X rows [bid*8, +8) to bf16
        __syncthreads();
        ushort* xbf = (ushort*)(wsF + WS_XBF);
        const int base = bid * 8 * NV;
        #pragma unroll
        for (int p = 0; p < 4; ++p) {
            const int off = base + tid * 4 + p * 1024;
            const float4 f = *(const float4*)(X + off);
            ushort4 o;
            o.x = f2bf(f.x); o.y = f2bf(f.y); o.z = f2bf(f.z); o.w = f2bf(f.w);
            *(ushort4*)(xbf + off) = o;
        }
    } else if (bid < 88) {
        // ---- convert masked W rows [ (bid-24)*8, +8) to bf16
        for (int l = tid; l < KC * KC; l += 256) Gs[l] = G[l];
        __syncthreads();
        ushort* wbf = (ushort*)(wsF + WS_WBF);
        const int i0 = (bid - 24) * 8;
        #pragma unroll
        for (int p = 0; p < 4; ++p) {
            const int l = tid * 4 + p * 1024;          // 0..4095 strip-local
            const int ir = i0 + (l >> 9), k = l & 511;
            const float* grow = Gs + asg[ir] * KC;
            const float4 f = *(const float4*)(W + ir * NV + k);
            ushort4 o;
            o.x = f2bf(f.x * grow[asg[k]]);
            o.y = f2bf(f.y * grow[asg[k + 1]]);
            o.z = f2bf(f.z * grow[asg[k + 2]]);
            o.w = f2bf(f.w * grow[asg[k + 3]]);
            *(ushort4*)(wbf + ir * NV + k) = o;
        }
    } else if (bid < 112) {
        // ---- X stats: 8 rows -> u partials, xx, per-row cluster sums -> sx1/sx2
        for (int l = tid; l < 8 * KC; l += 256) ((float*)smrows)[l] = 0.f;
        if (tid < 4) redw[tid] = 0.f;
        __syncthreads();
        const int sb = bid - 88, row0 = sb * 8;
        const int c0 = tid * 2;
        const int ca = asg[c0], cb = asg[c0 + 1];
        float u0 = 0.f, u1 = 0.f, xx = 0.f;
        #pragma unroll
        for (int r = 0; r < 8; ++r) {
            const float2 xv = *(const float2*)(X + (row0 + r) * NV + c0);
            u0 += xv.x; u1 += xv.y;
            xx += xv.x * xv.x + xv.y * xv.y;
            atomicAdd(&smrows[r][ca], xv.x);
            atomicAdd(&smrows[r][cb], xv.y);
        }
        for (int off = 32; off; off >>= 1) xx += __shfl_down(xx, off, 64);
        if ((tid & 63) == 0) redw[tid >> 6] = xx;
        __syncthreads();
        float* slice = wsF + WS_STATS + sb * 608;
        slice[c0] = u0; slice[c0 + 1] = u1;
        if (tid < KC) {
            float s1 = 0.f, s2 = 0.f;
            #pragma unroll
            for (int r = 0; r < 8; ++r) { const float s = smrows[r][tid]; s1 += s; s2 += s * s; }
            slice[512 + tid] = s1;
            slice[544 + tid] = s2;
        }
        if (tid == 0) slice[576] = redw[0] + redw[1] + redw[2] + redw[3];
    } else {
        // ---- prep: counts -> coef/logdet, persist asg, zero sm accumulator
        __shared__ int cnt[KC];
        __shared__ float ldred[KC];
        if (tid < KC) cnt[tid] = 0;
        __syncthreads();
        for (int n = tid; n < NV; n += 256) {
            atomicAdd(&cnt[asg[n]], 1);
            wsI[WS_ASG + n] = asg[n];
        }
        for (int l = tid; l < NB * KC; l += 256) wsF[WS_SM + l] = 0.f;
        __syncthreads();
        const float s2v = sigma[0] * sigma[0], rh = rho[0];
        const float av = s2v * (1.f - rh), bv = s2v * rh;
        if (tid < KC) {
            const int nc = cnt[tid];
            wsF[WS_P + tid] = bv / (av * (av + bv * (float)nc));
            ldred[tid] = (float)(nc - 1) * logf(av) + logf(av + bv * (float)nc);
        }
        __syncthreads();
        if (tid == 0) {
            float ld = 0.f;
            for (int c = 0; c < KC; ++c) ld += ldred[c];
            wsF[WS_P + 32] = ld;
        }
    }
}

// ---------------- node 2: MFMA GEMM, fragments direct from global ----------------
__global__ __launch_bounds__(256) void gemm_kernel(
    const float* __restrict__ bias, float* __restrict__ wsF, const int* __restrict__ wsI)
{
    const int bid = blockIdx.x, tid = threadIdx.x;
    const int blk_b = bid >> 3, blk_i = bid & 7;     // 12 b-tiles x 8 i-tiles
    const int b0 = blk_b * 16, i0blk = blk_i * 64;
    const int w = tid >> 6, lane = tid & 63;
    const int m = lane & 15, q = lane >> 4;
    const int i0w = i0blk + w * 16;

    __shared__ float smL[16 * KC];
    __shared__ float varr[64];
    __shared__ int asgc[64];
    __shared__ float mmred[4];
    for (int l = tid; l < 16 * KC; l += 256) smL[l] = 0.f;
    if (tid < 64) { varr[tid] = 0.f; asgc[tid] = wsI[WS_ASG + i0blk + tid]; }
    if (tid < 4) mmred[tid] = 0.f;

    const ushort* xbf = (const ushort*)(wsF + WS_XBF);
    const ushort* wbf = (const ushort*)(wsF + WS_WBF);
    const short8* ap = (const short8*)(xbf + (b0 + m) * NV + q * 8);
    const short8* bp = (const short8*)(wbf + (i0w + m) * NV + q * 8);
    float4v acc = {0.f, 0.f, 0.f, 0.f};
    #pragma unroll
    for (int s = 0; s < 16; ++s) {
        const short8 a = ap[s * 4];     // s*32 shorts = 4 short8
        const short8 b = bp[s * 4];
        acc = __builtin_amdgcn_mfma_f32_16x16x32_bf16(a, b, acc, 0, 0, 0);
    }
    __syncthreads();

    // epilogue: C/D layout col=lane&15, row=q*4+reg (m89-verified)
    const int col = i0w + m;
    const float bv = bias[col];
    const int ca = asgc[w * 16 + m];
    float vsum = 0.f, mml = 0.f;
    #pragma unroll
    for (int r = 0; r < 4; ++r) {
        const float val = acc[r] + bv;
        vsum += val; mml += val * val;
        atomicAdd(&smL[(q * 4 + r) * KC + ca], val);
    }
    atomicAdd(&varr[w * 16 + m], vsum);
    for (int off = 32; off; off >>= 1) mml += __shfl_down(mml, off, 64);
    if (lane == 0) mmred[w] = mml;
    __syncthreads();

    float* smG = wsF + WS_SM;
    for (int l = tid; l < 16 * KC; l += 256)
        atomicAdd(&smG[(b0 + (l >> 5)) * KC + (l & 31)], smL[l]);
    float* slice = wsF + WS_GV + bid * 65;
    if (tid < 64) slice[tid] = varr[tid];
    if (tid == 0) slice[64] = mmred[0] + mmred[1] + mmred[2] + mmred[3];
}

// ---------------- node 3: finalize ----------------
__global__ __launch_bounds__(256) void finalize_kernel(
    const float* __restrict__ sigma, const float* __restrict__ rho,
    const float* __restrict__ wsF, float* __restrict__ out)
{
    const int tid = threadIdx.x;
    __shared__ float SM1s[KC], SM2s[KC];
    __shared__ float accs[4];   // 0:MM 1:XX 2:cross(u.v) 3:Q
    if (tid < KC) { SM1s[tid] = 0.f; SM2s[tid] = 0.f; }
    if (tid < 4) accs[tid] = 0.f;
    __syncthreads();
    const float* sm = wsF + WS_SM;
    const float* gv = wsF + WS_GV;
    const float* st = wsF + WS_STATS;

    // SM1/SM2 over complete sm[192][32]
    {
        const int c = tid & 31, r0 = tid >> 5;     // 8 row-groups
        float s1 = 0.f, s2 = 0.f;
        #pragma unroll
        for (int j = 0; j < 24; ++j) {
            const float s = sm[(r0 + 8 * j) * KC + c];
            s1 += s; s2 += s * s;
        }
        atomicAdd(&SM1s[c], s1);
        atomicAdd(&SM2s[c], s2);
    }
    // u, v, cross term (2 cols per thread)
    {
        float cr = 0.f;
        #pragma unroll
        for (int h = 0; h < 2; ++h) {
            const int i = tid + h * 256;
            float u = 0.f;
            #pragma unroll
            for (int sb = 0; sb < 24; ++sb) u += st[sb * 608 + i];
            float v = 0.f;
            const int blk_i = i >> 6, loc = i & 63;
            #pragma unroll
            for (int bb = 0; bb < 12; ++bb) v += gv[(bb * 8 + blk_i) * 65 + loc];
            cr += u * v;
        }
        for (int off = 32; off; off >>= 1) cr += __shfl_down(cr, off, 64);
        if ((tid & 63) == 0) atomicAdd(&accs[2], cr);
    }
    // MM
    {
        float mm = (tid < 96) ? gv[tid * 65 + 64] : 0.f;
        for (int off = 32; off; off >>= 1) mm += __shfl_down(mm, off, 64);
        if ((tid & 63) == 0) atomicAdd(&accs[0], mm);
    }
    // XX
    {
        float xx = (tid < 24) ? st[tid * 608 + 576] : 0.f;
        for (int off = 32; off; off >>= 1) xx += __shfl_down(xx, off, 64);
        if ((tid & 63) == 0) atomicAdd(&accs[1], xx);
    }
    __syncthreads();
    // Q term
    {
        float qv = 0.f;
        if (tid < KC) {
            float s1 = 0.f, s2 = 0.f;
            #pragma unroll
            for (int sb = 0; sb < 24; ++sb) {
                s1 += st[sb * 608 + 512 + tid];
                s2 += st[sb * 608 + 544 + tid];
            }
            const float coef = wsF[WS_P + tid];
            qv = coef * (s2 * (1.f / NB) + SM2s[tid] * (1.f / NB)
                         - 2.f * s1 * SM1s[tid] * (1.f / ((float)NB * (float)NB)));
        }
        for (int off = 32; off; off >>= 1) qv += __shfl_down(qv, off, 64);
        if (tid == 0) atomicAdd(&accs[3], qv);
    }
    __syncthreads();
    if (tid == 0) {
        const float s2v = sigma[0] * sigma[0], rh = rho[0];
        const float av = s2v * (1.f - rh);
        const float meanD2 = accs[1] * (1.f / NB) + accs[0] * (1.f / NB)
                           - 2.f * accs[2] / ((float)NB * (float)NB);
        const float maha = meanD2 / av - accs[3];
        out[0] = -0.5f * (maha + wsF[WS_P + 32] + (float)NV * LOG2PI);
    }
}

extern "C" void kernel_launch(void* const* d_in, const int* in_sizes, int n_in,
                              void* d_out, int out_size, void* d_ws, size_t ws_size,
                              hipStream_t stream) {
    const float* X     = (const float*)d_in[0];
    const float* C     = (const float*)d_in[1];
    const float* G     = (const float*)d_in[2];
    const float* W     = (const float*)d_in[3];
    const float* b     = (const float*)d_in[4];
    const float* sigma = (const float*)d_in[5];
    const float* rho   = (const float*)d_in[6];
    float* wsF = (float*)d_ws;
    int*   wsI = (int*)d_ws;
    float* out = (float*)d_out;

    hipLaunchKernelGGL(prep_kernel, dim3(113), dim3(256), 0, stream,
                       X, C, G, W, b, sigma, rho, wsF, wsI);
    hipLaunchKernelGGL(gemm_kernel, dim3(96), dim3(256), 0, stream,
                       b, wsF, wsI);
    hipLaunchKernelGGL(finalize_kernel, dim3(1), dim3(256), 0, stream,
                       sigma, rho, wsF, out);
}